// Round 15
// baseline (259.767 us; speedup 1.0000x reference)
//
#include <hip/hip_runtime.h>
#include <stdint.h>

#define B_ 16
#define A_ 256
#define N_ 64
#define F_ 128
#define G_ 25
#define GP 32           // G padded to MFMA K=32
#define L_ 3
#define P_ (B_*A_)      // 4096 atoms
#define CUTOFF_ 5.0f
#define OFF0_ 1.2f

typedef float f32x4 __attribute__((ext_vector_type(4)));
typedef __bf16 bf16x8 __attribute__((ext_vector_type(8)));

__device__ __forceinline__ uint16_t f2bf(float f) {
    union { __bf16 b; uint16_t u; } v; v.b = (__bf16)f;  // RNE hw cvt
    return v.u;
}
// shifted softplus: log(1+e^x) - ln2. Fast form; inputs bounded (|x|<~20).
__device__ __forceinline__ float sspf(float x) {
    return fmaf(__log2f(1.0f + __expf(x)), 0.69314718055994531f,
                -0.69314718055994531f);
}

// ---- prep: transpose+pad all GEMM weights to bf16 [f][k] ----
__global__ void k_prepw(const float* __restrict__ fw1, const float* __restrict__ fw2,
                        const float* __restrict__ in2f, const float* __restrict__ f2ow,
                        const float* __restrict__ dnsw,
                        uint16_t* __restrict__ w1t, uint16_t* __restrict__ w2t,
                        uint16_t* __restrict__ in2ft, uint16_t* __restrict__ f2ot,
                        uint16_t* __restrict__ dnst) {
    int t = blockIdx.x * 256 + threadIdx.x;
    if (t < L_ * F_ * GP) {
        int k = t & (GP - 1); int f = (t >> 5) & (F_ - 1); int l = t >> 12;
        float v = (k < G_) ? fw1[(l * G_ + k) * F_ + f] : 0.0f;
        w1t[t] = f2bf(v);
    }
    if (t < L_ * F_ * F_) {
        int k = t & (F_ - 1); int f = (t >> 7) & (F_ - 1); int l = t >> 14;
        const size_t src = (size_t)(l * F_ + k) * F_ + f;
        w2t[t]   = f2bf(fw2[src]);
        in2ft[t] = f2bf(in2f[src]);
        f2ot[t]  = f2bf(f2ow[src]);
        dnst[t]  = f2bf(dnsw[src]);
    }
}

// ---- embed + first projection: x = emb[Z]; y0 = x @ in2f[0]^T (MFMA) ----
__global__ __launch_bounds__(256) void k_embed_proj(
        const float* __restrict__ emb, const int* __restrict__ Z,
        const uint16_t* __restrict__ in2ft0,
        float* __restrict__ x, float* __restrict__ y)
{
    const int wave = threadIdx.x >> 6;
    const int lane = threadIdx.x & 63;
    const int row  = lane & 15;
    const int kg   = lane >> 4;
    const int rb   = blockIdx.x * 64 + wave * 16;
    const int zr   = Z[rb + row];

    f32x4 acc[8];
#pragma unroll
    for (int nt = 0; nt < 8; ++nt) acc[nt] = (f32x4){0.f, 0.f, 0.f, 0.f};
#pragma unroll
    for (int ks = 0; ks < 4; ++ks) {
        const float* ep = emb + (size_t)zr * F_ + ks * 32 + kg * 8;
        float4 e0 = *(const float4*)ep;
        float4 e1 = *(const float4*)(ep + 4);
        bf16x8 a;
        a[0] = (__bf16)e0.x; a[1] = (__bf16)e0.y; a[2] = (__bf16)e0.z; a[3] = (__bf16)e0.w;
        a[4] = (__bf16)e1.x; a[5] = (__bf16)e1.y; a[6] = (__bf16)e1.z; a[7] = (__bf16)e1.w;
#pragma unroll
        for (int nt = 0; nt < 8; ++nt) {
            bf16x8 bfr = *(const bf16x8*)(in2ft0 + (nt * 16 + row) * F_ + ks * 32 + kg * 8);
            acc[nt] = __builtin_amdgcn_mfma_f32_16x16x32_bf16(a, bfr, acc[nt], 0, 0, 0);
        }
    }
#pragma unroll
    for (int nt = 0; nt < 8; ++nt)
#pragma unroll
        for (int j = 0; j < 4; ++j)
            y[(size_t)(rb + kg * 4 + j) * F_ + nt * 16 + row] = acc[nt][j];

    // coalesced x write (embedding gather, L1-hot after A-frag loads)
    const int rb0 = blockIdx.x * 64;
#pragma unroll
    for (int i = 0; i < 32; ++i) {
        int idx = i * 256 + threadIdx.x;      // 0..8191
        int p = rb0 + (idx >> 7), f = idx & 127;
        x[(size_t)p * F_ + f] = emb[(size_t)Z[p] * F_ + f];
    }
}

// ---- fully fused layer: CFConv + atom MLP + next-layer projection ----
// WG = 768 thr = 12 waves = 3 atoms. Phase2 (per-wave edge tile, barrier-free,
// y-gather issued EARLY) -> psum in LDS -> col-split MLP tail on waves 0..7.
// launch_bounds(768,6): 6 waves/SIMD = 2 WG/CU (matches 80KB LDS cap),
// VGPR budget ~85 so the y-prefetch stays in registers.
__global__ __launch_bounds__(768, 6) void k_layer_full(
        const float* __restrict__ pos, const int* __restrict__ nbr,
        const float* __restrict__ mask, const float* __restrict__ y,
        const uint16_t* __restrict__ w1t, const float* __restrict__ b1,
        const uint16_t* __restrict__ w2t, const float* __restrict__ b2,
        const uint16_t* __restrict__ f2ot, const float* __restrict__ ba,
        const uint16_t* __restrict__ dnst, const float* __restrict__ bb,
        const uint16_t* __restrict__ in2ftN,   // next-layer proj weights or null
        float* __restrict__ x, float* __restrict__ yout, float* __restrict__ out)
{
    __shared__ uint16_t w2s[F_ * F_];             // 32 KB swizzled
    __shared__ __align__(16) unsigned char ar[12 * 4096];  // h1 / psum / mlp arena

    // ---- cooperative w2 staging ----
    {
        const int t = threadIdx.x;
#pragma unroll
        for (int i = 0; i < 3; ++i) {
            const int idx = i * 768 + t;
            if (idx < 2048) {
                const int f2 = idx >> 4, kc2 = (idx & 15) * 8;
                uint4 v2 = *(const uint4*)(w2t + f2 * F_ + kc2);
                *(uint4*)((char*)w2s + f2 * 256 + ((kc2 * 2) ^ ((f2 & 7) << 4))) = v2;
            }
        }
    }
    __syncthreads();   // barrier 1

    const int wave = threadIdx.x >> 6;
    const int lane = threadIdx.x & 63;
    const int row  = lane & 15;
    const int kg   = lane >> 4;
    const int a0   = blockIdx.x * 3;
    const int valid = (P_ - a0 < 3) ? (P_ - a0) : 3;
    const int aidx = wave >> 2;            // atom within WG (0..2)
    const int atom = a0 + aidx;
    const int tile = wave & 3;

    uint16_t* hl = (uint16_t*)(ar + wave * 4096);

    if (aidx < valid) {
        const int molbase = atom & ~(A_ - 1);

        // --- neighbor indices first; issue the 32-float y-gather EARLY ---
        const int e_mine = atom * N_ + tile * 16 + row;
        const int jrow_mine = molbase + nbr[e_mine];
        int jr[4];
#pragma unroll
        for (int j = 0; j < 4; ++j) jr[j] = __shfl(jrow_mine, kg * 4 + j);
        float yv[8][4];
#pragma unroll
        for (int nt = 0; nt < 8; ++nt)
#pragma unroll
            for (int j = 0; j < 4; ++j)
                yv[nt][j] = y[(size_t)jr[j] * F_ + nt * 16 + row];
        // loads stay vmcnt-pending under RBF + GEMM1 + ssp + GEMM2

        // --- RBF ---
        const float px = pos[atom * 3 + 0];
        const float py = pos[atom * 3 + 1];
        const float pz = pos[atom * 3 + 2];
        const float dx = pos[jrow_mine * 3 + 0] - px;
        const float dy = pos[jrow_mine * 3 + 1] - py;
        const float dz = pos[jrow_mine * 3 + 2] - pz;
        const float r = sqrtf(dx * dx + dy * dy + dz * dz + 1e-9f);
        const float fcr = (r <= CUTOFF_) ? mask[e_mine] : 0.0f;
        const float step = 3.8f / 24.0f;
        const float coef = -0.5f / (step * step);
        bf16x8 a1v;
#pragma unroll
        for (int j = 0; j < 8; ++j) {
            const int k = kg * 8 + j;
            float val = 0.0f;
            if (k < G_) { const float d = r - (OFF0_ + step * (float)k); val = __expf(coef * d * d); }
            a1v[j] = (__bf16)val;
        }

        // GEMM1 -> ssp -> swizzled per-wave h1
#pragma unroll
        for (int nt = 0; nt < 8; ++nt) {
            const float b1v = b1[nt * 16 + row];
            const f32x4 c1 = {b1v, b1v, b1v, b1v};
            bf16x8 bfr = *(const bf16x8*)(w1t + (nt * 16 + row) * GP + kg * 8);
            f32x4 acc1 = __builtin_amdgcn_mfma_f32_16x16x32_bf16(a1v, bfr, c1, 0, 0, 0);
            const int col = nt * 16 + row;
#pragma unroll
            for (int j = 0; j < 4; ++j) {
                const int rr = kg * 4 + j;
                const int byt = rr * 256 + ((col * 2) ^ ((rr & 7) << 4));
                *(uint16_t*)((char*)hl + byt) = f2bf(sspf(acc1[j]));
            }
        }

        // GEMM2 (B from w2s)
        f32x4 acc2[8];
#pragma unroll
        for (int nt = 0; nt < 8; ++nt) {
            const float b2v = b2[nt * 16 + row];
            acc2[nt] = (f32x4){b2v, b2v, b2v, b2v};
        }
#pragma unroll
        for (int ks = 0; ks < 4; ++ks) {
            const int kbyte = ks * 64 + kg * 16;
            bf16x8 a2 = *(const bf16x8*)((char*)hl + row * 256 + (kbyte ^ ((row & 7) << 4)));
#pragma unroll
            for (int nt = 0; nt < 8; ++nt) {
                bf16x8 bfr = *(const bf16x8*)((char*)w2s + (nt * 16 + row) * 256 +
                                              (kbyte ^ ((row & 7) << 4)));
                acc2[nt] = __builtin_amdgcn_mfma_f32_16x16x32_bf16(a2, bfr, acc2[nt], 0, 0, 0);
            }
        }

        // epilogue: mask, prefetched-y modulate, cross-kg reduce -> psum
        float fc[4];
#pragma unroll
        for (int j = 0; j < 4; ++j) fc[j] = __shfl(fcr, kg * 4 + j);
        float* psum = (float*)hl;   // h1 rows already consumed
#pragma unroll
        for (int nt = 0; nt < 8; ++nt) {
            const int col = nt * 16 + row;
            float s = 0.0f;
#pragma unroll
            for (int j = 0; j < 4; ++j)
                s += (acc2[nt][j] * fc[j]) * yv[nt][j];
            s += __shfl_xor(s, 16);
            s += __shfl_xor(s, 32);
            if (kg == 0) psum[col] = s;
        }
    }
    __syncthreads();   // barrier 2: all psum written, h1 dead

    // ---- pre-sum 4 tiles -> bf16 abf (stride 136 u16: bank-spread rows) ----
    {
        const int t = threadIdx.x;
        if (t < 384) {
            const int a = t >> 7, f = t & 127;
            float s = 0.f;
#pragma unroll
            for (int tt = 0; tt < 4; ++tt)
                s += ((const float*)(ar + (a * 4 + tt) * 4096))[f];
            ((uint16_t*)(ar + 2048))[a * 136 + f] = f2bf(s);
        }
    }
    __syncthreads();   // barrier 3

    const uint16_t* abf = (const uint16_t*)(ar + 2048);  // stride 136
    uint16_t* mlpH = (uint16_t*)(ar + 4096);
    float*    mlpX = (float*)(ar + 8192);                // stride 136
    const int fcol = wave * 16 + row;      // this wave's output column
    const int rcl  = (row < 3) ? row : 3;  // clamped A-row (atom) index

    // GEMM_a: H = ssp(abf @ f2o + ba)  (waves 0..7, col tile nt = wave)
    if (wave < 8) {
        const float bav = ba[fcol];
        f32x4 acc = {bav, bav, bav, bav};
#pragma unroll
        for (int ks = 0; ks < 4; ++ks) {
            bf16x8 a = *(const bf16x8*)(abf + rcl * 136 + ks * 32 + kg * 8);
            bf16x8 bfr = *(const bf16x8*)(f2ot + fcol * F_ + ks * 32 + kg * 8);
            acc = __builtin_amdgcn_mfma_f32_16x16x32_bf16(a, bfr, acc, 0, 0, 0);
        }
#pragma unroll
        for (int j = 0; j < 4; ++j) {
            const int rr = kg * 4 + j;
            const int byt = rr * 256 + ((fcol * 2) ^ ((rr & 7) << 4));
            *(uint16_t*)((char*)mlpH + byt) = f2bf(sspf(acc[j]));
        }
    }
    __syncthreads();   // barrier 4

    // GEMM_b: x_new = H @ dns + bb + x  (waves 0..7)
    if (wave < 8) {
        const float bbv = bb[fcol];
        f32x4 acc = {bbv, bbv, bbv, bbv};
#pragma unroll
        for (int ks = 0; ks < 4; ++ks) {
            const int kbyte = ks * 64 + kg * 16;
            bf16x8 a2 = *(const bf16x8*)((char*)mlpH + row * 256 + (kbyte ^ ((row & 7) << 4)));
            bf16x8 bfr = *(const bf16x8*)(dnst + fcol * F_ + ks * 32 + kg * 8);
            acc = __builtin_amdgcn_mfma_f32_16x16x32_bf16(a2, bfr, acc, 0, 0, 0);
        }
        if (kg == 0) {
#pragma unroll
            for (int j = 0; j < 3; ++j) {
                if (j < valid) {
                    const size_t idx = (size_t)(a0 + j) * F_ + fcol;
                    const float val = acc[j] + x[idx];
                    x[idx] = val;
                    mlpX[j * 136 + fcol] = val;
                    if (out) out[idx] = val;
                }
            }
        }
    }

    // GEMM_c: y_next = x_new @ in2f[l+1]  (waves 0..7)
    if (in2ftN) {
        __syncthreads();   // barrier 5 (uniform branch)
        if (wave < 8) {
            f32x4 acc = {0.f, 0.f, 0.f, 0.f};
#pragma unroll
            for (int ks = 0; ks < 4; ++ks) {
                const float* xp = mlpX + rcl * 136 + ks * 32 + kg * 8;
                float4 u0 = *(const float4*)xp;
                float4 u1 = *(const float4*)(xp + 4);
                bf16x8 a;
                a[0] = (__bf16)u0.x; a[1] = (__bf16)u0.y; a[2] = (__bf16)u0.z; a[3] = (__bf16)u0.w;
                a[4] = (__bf16)u1.x; a[5] = (__bf16)u1.y; a[6] = (__bf16)u1.z; a[7] = (__bf16)u1.w;
                bf16x8 bfr = *(const bf16x8*)(in2ftN + fcol * F_ + ks * 32 + kg * 8);
                acc = __builtin_amdgcn_mfma_f32_16x16x32_bf16(a, bfr, acc, 0, 0, 0);
            }
            if (kg == 0) {
#pragma unroll
                for (int j = 0; j < 3; ++j)
                    if (j < valid)
                        yout[(size_t)(a0 + j) * F_ + fcol] = acc[j];
            }
        }
    }
}

extern "C" void kernel_launch(void* const* d_in, const int* in_sizes, int n_in,
                              void* d_out, int out_size, void* d_ws, size_t ws_size,
                              hipStream_t stream) {
    const float* emb   = (const float*)d_in[0];
    const float* pos   = (const float*)d_in[1];
    const float* fw1   = (const float*)d_in[2];
    const float* fb1   = (const float*)d_in[3];
    const float* fw2   = (const float*)d_in[4];
    const float* fb2   = (const float*)d_in[5];
    const float* in2f  = (const float*)d_in[6];
    const float* f2o_w = (const float*)d_in[7];
    const float* f2o_b = (const float*)d_in[8];
    const float* dns_w = (const float*)d_in[9];
    const float* dns_b = (const float*)d_in[10];
    const int*   Z     = (const int*)d_in[11];
    const int*   nbrs  = (const int*)d_in[12];
    const float* mask  = (const float*)d_in[13];

    char* ws = (char*)d_ws;
    size_t off = 0;
    auto alloc = [&](size_t bytes) {
        char* p = ws + off; off += (bytes + 255) & ~(size_t)255; return p;
    };
    float*    x     = (float*)   alloc((size_t)P_ * F_ * 4);
    float*    y0    = (float*)   alloc((size_t)P_ * F_ * 4);
    float*    y1    = (float*)   alloc((size_t)P_ * F_ * 4);
    uint16_t* w1t   = (uint16_t*)alloc((size_t)L_ * F_ * GP * 2);
    uint16_t* w2t   = (uint16_t*)alloc((size_t)L_ * F_ * F_ * 2);
    uint16_t* in2ft = (uint16_t*)alloc((size_t)L_ * F_ * F_ * 2);
    uint16_t* f2ot  = (uint16_t*)alloc((size_t)L_ * F_ * F_ * 2);
    uint16_t* dnst  = (uint16_t*)alloc((size_t)L_ * F_ * F_ * 2);
    // total scratch: ~6.8 MB

    k_prepw<<<192, 256, 0, stream>>>(fw1, fw2, in2f, f2o_w, dns_w,
                                     w1t, w2t, in2ft, f2ot, dnst);
    k_embed_proj<<<P_ / 64, 256, 0, stream>>>(emb, Z, in2ft, x, y0);

    const int nwg = (P_ + 2) / 3;   // 1366
    float* ycur = y0;
    float* ynxt = y1;
    for (int l = 0; l < L_; ++l) {
        k_layer_full<<<nwg, 768, 0, stream>>>(
            pos, nbrs, mask, ycur,
            w1t + (size_t)l * F_ * GP, fb1 + (size_t)l * F_,
            w2t + (size_t)l * F_ * F_, fb2 + (size_t)l * F_,
            f2ot + (size_t)l * F_ * F_, f2o_b + (size_t)l * F_,
            dnst + (size_t)l * F_ * F_, dns_b + (size_t)l * F_,
            (l < L_ - 1) ? (in2ft + (size_t)(l + 1) * F_ * F_) : nullptr,
            x, ynxt, (l == L_ - 1) ? (float*)d_out : nullptr);
        float* t = ycur; ycur = ynxt; ynxt = t;
    }
}

// Round 16
// 148.824 us; speedup vs baseline: 1.7455x; 1.7455x over previous
//
#include <hip/hip_runtime.h>
#include <stdint.h>

#define B_ 16
#define A_ 256
#define N_ 64
#define F_ 128
#define G_ 25
#define GP 32           // G padded to MFMA K=32
#define L_ 3
#define P_ (B_*A_)      // 4096 atoms
#define CUTOFF_ 5.0f
#define OFF0_ 1.2f
#define NWG_ ((P_ + 2) / 3)   // 1366 workgroups for k_layer_full

typedef float f32x4 __attribute__((ext_vector_type(4)));
typedef __bf16 bf16x8 __attribute__((ext_vector_type(8)));

__device__ __forceinline__ uint16_t f2bf(float f) {
    union { __bf16 b; uint16_t u; } v; v.b = (__bf16)f;  // RNE hw cvt
    return v.u;
}
// shifted softplus: log(1+e^x) - ln2. Fast form; inputs bounded (|x|<~20).
__device__ __forceinline__ float sspf(float x) {
    return fmaf(__log2f(1.0f + __expf(x)), 0.69314718055994531f,
                -0.69314718055994531f);
}
// bijective XCD-chunking swizzle (m204): contiguous ranges per XCD
__device__ __forceinline__ int xcd_swizzle(int bid, int nwg) {
    const int q = nwg >> 3, r = nwg & 7;
    const int xcd = bid & 7, idx = bid >> 3;
    const int base = (xcd < r) ? xcd * (q + 1) : r * (q + 1) + (xcd - r) * q;
    return base + idx;
}

// ---- prep: transpose+pad all GEMM weights to bf16 [f][k] ----
__global__ void k_prepw(const float* __restrict__ fw1, const float* __restrict__ fw2,
                        const float* __restrict__ in2f, const float* __restrict__ f2ow,
                        const float* __restrict__ dnsw,
                        uint16_t* __restrict__ w1t, uint16_t* __restrict__ w2t,
                        uint16_t* __restrict__ in2ft, uint16_t* __restrict__ f2ot,
                        uint16_t* __restrict__ dnst) {
    int t = blockIdx.x * 256 + threadIdx.x;
    if (t < L_ * F_ * GP) {
        int k = t & (GP - 1); int f = (t >> 5) & (F_ - 1); int l = t >> 12;
        float v = (k < G_) ? fw1[(l * G_ + k) * F_ + f] : 0.0f;
        w1t[t] = f2bf(v);
    }
    if (t < L_ * F_ * F_) {
        int k = t & (F_ - 1); int f = (t >> 7) & (F_ - 1); int l = t >> 14;
        const size_t src = (size_t)(l * F_ + k) * F_ + f;
        w2t[t]   = f2bf(fw2[src]);
        in2ft[t] = f2bf(in2f[src]);
        f2ot[t]  = f2bf(f2ow[src]);
        dnst[t]  = f2bf(dnsw[src]);
    }
}

// ---- embed + first projection: x = emb[Z]; y0 = x @ in2f[0]^T (MFMA) ----
__global__ __launch_bounds__(256) void k_embed_proj(
        const float* __restrict__ emb, const int* __restrict__ Z,
        const uint16_t* __restrict__ in2ft0,
        float* __restrict__ x, float* __restrict__ y)
{
    const int wave = threadIdx.x >> 6;
    const int lane = threadIdx.x & 63;
    const int row  = lane & 15;
    const int kg   = lane >> 4;
    const int rb   = blockIdx.x * 64 + wave * 16;
    const int zr   = Z[rb + row];

    f32x4 acc[8];
#pragma unroll
    for (int nt = 0; nt < 8; ++nt) acc[nt] = (f32x4){0.f, 0.f, 0.f, 0.f};
#pragma unroll
    for (int ks = 0; ks < 4; ++ks) {
        const float* ep = emb + (size_t)zr * F_ + ks * 32 + kg * 8;
        float4 e0 = *(const float4*)ep;
        float4 e1 = *(const float4*)(ep + 4);
        bf16x8 a;
        a[0] = (__bf16)e0.x; a[1] = (__bf16)e0.y; a[2] = (__bf16)e0.z; a[3] = (__bf16)e0.w;
        a[4] = (__bf16)e1.x; a[5] = (__bf16)e1.y; a[6] = (__bf16)e1.z; a[7] = (__bf16)e1.w;
#pragma unroll
        for (int nt = 0; nt < 8; ++nt) {
            bf16x8 bfr = *(const bf16x8*)(in2ft0 + (nt * 16 + row) * F_ + ks * 32 + kg * 8);
            acc[nt] = __builtin_amdgcn_mfma_f32_16x16x32_bf16(a, bfr, acc[nt], 0, 0, 0);
        }
    }
#pragma unroll
    for (int nt = 0; nt < 8; ++nt)
#pragma unroll
        for (int j = 0; j < 4; ++j)
            y[(size_t)(rb + kg * 4 + j) * F_ + nt * 16 + row] = acc[nt][j];

    // coalesced x write (embedding gather, L1-hot after A-frag loads)
    const int rb0 = blockIdx.x * 64;
#pragma unroll
    for (int i = 0; i < 32; ++i) {
        int idx = i * 256 + threadIdx.x;      // 0..8191
        int p = rb0 + (idx >> 7), f = idx & 127;
        x[(size_t)p * F_ + f] = emb[(size_t)Z[p] * F_ + f];
    }
}

// ---- fully fused layer: CFConv + atom MLP + next-layer projection ----
// WG = 768 thr = 12 waves = 3 atoms. Phase2 (per-wave edge tile, barrier-free)
// -> psum in LDS -> col-split MLP tail on waves 0..7 (nt = wave).
// blockIdx XCD-swizzled: neighbor WGs (same molecule) share y rows in L2.
__global__ __launch_bounds__(768) void k_layer_full(
        const float* __restrict__ pos, const int* __restrict__ nbr,
        const float* __restrict__ mask, const float* __restrict__ y,
        const uint16_t* __restrict__ w1t, const float* __restrict__ b1,
        const uint16_t* __restrict__ w2t, const float* __restrict__ b2,
        const uint16_t* __restrict__ f2ot, const float* __restrict__ ba,
        const uint16_t* __restrict__ dnst, const float* __restrict__ bb,
        const uint16_t* __restrict__ in2ftN,   // next-layer proj weights or null
        float* __restrict__ x, float* __restrict__ yout, float* __restrict__ out)
{
    __shared__ uint16_t w2s[F_ * F_];             // 32 KB swizzled
    __shared__ __align__(16) unsigned char ar[12 * 4096];  // h1 / psum / mlp arena

    // ---- cooperative w2 staging ----
    {
        const int t = threadIdx.x;
#pragma unroll
        for (int i = 0; i < 3; ++i) {
            const int idx = i * 768 + t;
            if (idx < 2048) {
                const int f2 = idx >> 4, kc2 = (idx & 15) * 8;
                uint4 v2 = *(const uint4*)(w2t + f2 * F_ + kc2);
                *(uint4*)((char*)w2s + f2 * 256 + ((kc2 * 2) ^ ((f2 & 7) << 4))) = v2;
            }
        }
    }
    __syncthreads();   // barrier 1

    const int bid  = xcd_swizzle(blockIdx.x, NWG_);
    const int wave = threadIdx.x >> 6;
    const int lane = threadIdx.x & 63;
    const int row  = lane & 15;
    const int kg   = lane >> 4;
    const int a0   = bid * 3;
    const int valid = (P_ - a0 < 3) ? (P_ - a0) : 3;
    const int aidx = wave >> 2;            // atom within WG (0..2)
    const int atom = a0 + aidx;
    const int tile = wave & 3;

    uint16_t* hl = (uint16_t*)(ar + wave * 4096);

    if (aidx < valid) {
        const int molbase = atom & ~(A_ - 1);
        const float px = pos[atom * 3 + 0];
        const float py = pos[atom * 3 + 1];
        const float pz = pos[atom * 3 + 2];

        const int e_mine = atom * N_ + tile * 16 + row;
        const int jrow_mine = molbase + nbr[e_mine];
        const float dx = pos[jrow_mine * 3 + 0] - px;
        const float dy = pos[jrow_mine * 3 + 1] - py;
        const float dz = pos[jrow_mine * 3 + 2] - pz;
        const float r = sqrtf(dx * dx + dy * dy + dz * dz + 1e-9f);
        const float fcr = (r <= CUTOFF_) ? mask[e_mine] : 0.0f;
        const float step = 3.8f / 24.0f;
        const float coef = -0.5f / (step * step);
        bf16x8 a1v;
#pragma unroll
        for (int j = 0; j < 8; ++j) {
            const int k = kg * 8 + j;
            float val = 0.0f;
            if (k < G_) { const float d = r - (OFF0_ + step * (float)k); val = __expf(coef * d * d); }
            a1v[j] = (__bf16)val;
        }

        // GEMM1 -> ssp -> swizzled per-wave h1
#pragma unroll
        for (int nt = 0; nt < 8; ++nt) {
            const float b1v = b1[nt * 16 + row];
            const f32x4 c1 = {b1v, b1v, b1v, b1v};
            bf16x8 bfr = *(const bf16x8*)(w1t + (nt * 16 + row) * GP + kg * 8);
            f32x4 acc1 = __builtin_amdgcn_mfma_f32_16x16x32_bf16(a1v, bfr, c1, 0, 0, 0);
            const int col = nt * 16 + row;
#pragma unroll
            for (int j = 0; j < 4; ++j) {
                const int rr = kg * 4 + j;
                const int byt = rr * 256 + ((col * 2) ^ ((rr & 7) << 4));
                *(uint16_t*)((char*)hl + byt) = f2bf(sspf(acc1[j]));
            }
        }

        // GEMM2 (B from w2s)
        f32x4 acc2[8];
#pragma unroll
        for (int nt = 0; nt < 8; ++nt) {
            const float b2v = b2[nt * 16 + row];
            acc2[nt] = (f32x4){b2v, b2v, b2v, b2v};
        }
#pragma unroll
        for (int ks = 0; ks < 4; ++ks) {
            const int kbyte = ks * 64 + kg * 16;
            bf16x8 a2 = *(const bf16x8*)((char*)hl + row * 256 + (kbyte ^ ((row & 7) << 4)));
#pragma unroll
            for (int nt = 0; nt < 8; ++nt) {
                bf16x8 bfr = *(const bf16x8*)((char*)w2s + (nt * 16 + row) * 256 +
                                              (kbyte ^ ((row & 7) << 4)));
                acc2[nt] = __builtin_amdgcn_mfma_f32_16x16x32_bf16(a2, bfr, acc2[nt], 0, 0, 0);
            }
        }

        // epilogue: mask, y-gather modulate, cross-kg reduce -> psum (own h1)
        float fc[4]; int jr[4];
#pragma unroll
        for (int j = 0; j < 4; ++j) {
            fc[j] = __shfl(fcr, kg * 4 + j);
            jr[j] = __shfl(jrow_mine, kg * 4 + j);
        }
        float* psum = (float*)hl;   // h1 rows already consumed
#pragma unroll
        for (int nt = 0; nt < 8; ++nt) {
            const int col = nt * 16 + row;
            float s = 0.0f;
#pragma unroll
            for (int j = 0; j < 4; ++j)
                s += (acc2[nt][j] * fc[j]) * y[jr[j] * F_ + col];
            s += __shfl_xor(s, 16);
            s += __shfl_xor(s, 32);
            if (kg == 0) psum[col] = s;
        }
    }
    __syncthreads();   // barrier 2: all psum written, h1 dead

    // ---- pre-sum 4 tiles -> bf16 abf (stride 136 u16: bank-spread rows) ----
    {
        const int t = threadIdx.x;
        if (t < 384) {
            const int a = t >> 7, f = t & 127;
            float s = 0.f;
#pragma unroll
            for (int tt = 0; tt < 4; ++tt)
                s += ((const float*)(ar + (a * 4 + tt) * 4096))[f];
            ((uint16_t*)(ar + 2048))[a * 136 + f] = f2bf(s);
        }
    }
    __syncthreads();   // barrier 3

    const uint16_t* abf = (const uint16_t*)(ar + 2048);  // stride 136
    uint16_t* mlpH = (uint16_t*)(ar + 4096);
    float*    mlpX = (float*)(ar + 8192);                // stride 136
    const int fcol = wave * 16 + row;      // this wave's output column
    const int rcl  = (row < 3) ? row : 3;  // clamped A-row (atom) index

    // GEMM_a: H = ssp(abf @ f2o + ba)  (waves 0..7, col tile nt = wave)
    if (wave < 8) {
        const float bav = ba[fcol];
        f32x4 acc = {bav, bav, bav, bav};
#pragma unroll
        for (int ks = 0; ks < 4; ++ks) {
            bf16x8 a = *(const bf16x8*)(abf + rcl * 136 + ks * 32 + kg * 8);
            bf16x8 bfr = *(const bf16x8*)(f2ot + fcol * F_ + ks * 32 + kg * 8);
            acc = __builtin_amdgcn_mfma_f32_16x16x32_bf16(a, bfr, acc, 0, 0, 0);
        }
#pragma unroll
        for (int j = 0; j < 4; ++j) {
            const int rr = kg * 4 + j;
            const int byt = rr * 256 + ((fcol * 2) ^ ((rr & 7) << 4));
            *(uint16_t*)((char*)mlpH + byt) = f2bf(sspf(acc[j]));
        }
    }
    __syncthreads();   // barrier 4

    // GEMM_b: x_new = H @ dns + bb + x  (waves 0..7)
    if (wave < 8) {
        const float bbv = bb[fcol];
        f32x4 acc = {bbv, bbv, bbv, bbv};
#pragma unroll
        for (int ks = 0; ks < 4; ++ks) {
            const int kbyte = ks * 64 + kg * 16;
            bf16x8 a2 = *(const bf16x8*)((char*)mlpH + row * 256 + (kbyte ^ ((row & 7) << 4)));
            bf16x8 bfr = *(const bf16x8*)(dnst + fcol * F_ + ks * 32 + kg * 8);
            acc = __builtin_amdgcn_mfma_f32_16x16x32_bf16(a2, bfr, acc, 0, 0, 0);
        }
        if (kg == 0) {
#pragma unroll
            for (int j = 0; j < 3; ++j) {
                if (j < valid) {
                    const size_t idx = (size_t)(a0 + j) * F_ + fcol;
                    const float val = acc[j] + x[idx];
                    x[idx] = val;
                    mlpX[j * 136 + fcol] = val;
                    if (out) out[idx] = val;
                }
            }
        }
    }

    // GEMM_c: y_next = x_new @ in2f[l+1]  (waves 0..7)
    if (in2ftN) {
        __syncthreads();   // barrier 5 (uniform branch)
        if (wave < 8) {
            f32x4 acc = {0.f, 0.f, 0.f, 0.f};
#pragma unroll
            for (int ks = 0; ks < 4; ++ks) {
                const float* xp = mlpX + rcl * 136 + ks * 32 + kg * 8;
                float4 u0 = *(const float4*)xp;
                float4 u1 = *(const float4*)(xp + 4);
                bf16x8 a;
                a[0] = (__bf16)u0.x; a[1] = (__bf16)u0.y; a[2] = (__bf16)u0.z; a[3] = (__bf16)u0.w;
                a[4] = (__bf16)u1.x; a[5] = (__bf16)u1.y; a[6] = (__bf16)u1.z; a[7] = (__bf16)u1.w;
                bf16x8 bfr = *(const bf16x8*)(in2ftN + fcol * F_ + ks * 32 + kg * 8);
                acc = __builtin_amdgcn_mfma_f32_16x16x32_bf16(a, bfr, acc, 0, 0, 0);
            }
            if (kg == 0) {
#pragma unroll
                for (int j = 0; j < 3; ++j)
                    if (j < valid)
                        yout[(size_t)(a0 + j) * F_ + fcol] = acc[j];
            }
        }
    }
}

extern "C" void kernel_launch(void* const* d_in, const int* in_sizes, int n_in,
                              void* d_out, int out_size, void* d_ws, size_t ws_size,
                              hipStream_t stream) {
    const float* emb   = (const float*)d_in[0];
    const float* pos   = (const float*)d_in[1];
    const float* fw1   = (const float*)d_in[2];
    const float* fb1   = (const float*)d_in[3];
    const float* fw2   = (const float*)d_in[4];
    const float* fb2   = (const float*)d_in[5];
    const float* in2f  = (const float*)d_in[6];
    const float* f2o_w = (const float*)d_in[7];
    const float* f2o_b = (const float*)d_in[8];
    const float* dns_w = (const float*)d_in[9];
    const float* dns_b = (const float*)d_in[10];
    const int*   Z     = (const int*)d_in[11];
    const int*   nbrs  = (const int*)d_in[12];
    const float* mask  = (const float*)d_in[13];

    char* ws = (char*)d_ws;
    size_t off = 0;
    auto alloc = [&](size_t bytes) {
        char* p = ws + off; off += (bytes + 255) & ~(size_t)255; return p;
    };
    float*    x     = (float*)   alloc((size_t)P_ * F_ * 4);
    float*    y0    = (float*)   alloc((size_t)P_ * F_ * 4);
    float*    y1    = (float*)   alloc((size_t)P_ * F_ * 4);
    uint16_t* w1t   = (uint16_t*)alloc((size_t)L_ * F_ * GP * 2);
    uint16_t* w2t   = (uint16_t*)alloc((size_t)L_ * F_ * F_ * 2);
    uint16_t* in2ft = (uint16_t*)alloc((size_t)L_ * F_ * F_ * 2);
    uint16_t* f2ot  = (uint16_t*)alloc((size_t)L_ * F_ * F_ * 2);
    uint16_t* dnst  = (uint16_t*)alloc((size_t)L_ * F_ * F_ * 2);
    // total scratch: ~6.8 MB

    k_prepw<<<192, 256, 0, stream>>>(fw1, fw2, in2f, f2o_w, dns_w,
                                     w1t, w2t, in2ft, f2ot, dnst);
    k_embed_proj<<<P_ / 64, 256, 0, stream>>>(emb, Z, in2ft, x, y0);

    float* ycur = y0;
    float* ynxt = y1;
    for (int l = 0; l < L_; ++l) {
        k_layer_full<<<NWG_, 768, 0, stream>>>(
            pos, nbrs, mask, ycur,
            w1t + (size_t)l * F_ * GP, fb1 + (size_t)l * F_,
            w2t + (size_t)l * F_ * F_, fb2 + (size_t)l * F_,
            f2ot + (size_t)l * F_ * F_, f2o_b + (size_t)l * F_,
            dnst + (size_t)l * F_ * F_, dns_b + (size_t)l * F_,
            (l < L_ - 1) ? (in2ft + (size_t)(l + 1) * F_ * F_) : nullptr,
            x, ynxt, (l == L_ - 1) ? (float*)d_out : nullptr);
        float* t = ycur; ycur = ynxt; ynxt = t;
    }
}

// Round 17
// 100.488 us; speedup vs baseline: 2.5850x; 1.4810x over previous
//
#include <hip/hip_runtime.h>
#include <stdint.h>

#define B_ 16
#define A_ 256
#define N_ 64
#define F_ 128
#define G_ 25
#define L_ 3
#define P_ (B_*A_)      // 4096 atoms
#define CUTOFF_ 5.0f
#define OFF0_ 1.2f
#define NT_ 2048                      // filter table rows
#define DELTA_ (5.0f / 2047.0f)
#define INVD_ (2047.0f / 5.0f)
#define NWG_ (P_ / 8)                 // 512 workgroups for k_layer_full

typedef float f32x4 __attribute__((ext_vector_type(4)));
typedef __bf16 bf16x8 __attribute__((ext_vector_type(8)));

__device__ __forceinline__ uint16_t f2bf(float f) {
    union { __bf16 b; uint16_t u; } v; v.b = (__bf16)f;  // RNE hw cvt
    return v.u;
}
// shifted softplus: log(1+e^x) - ln2. Fast form; inputs bounded (|x|<~20).
__device__ __forceinline__ float sspf(float x) {
    return fmaf(__log2f(1.0f + __expf(x)), 0.69314718055994531f,
                -0.69314718055994531f);
}
// bijective XCD-chunking swizzle (m204): contiguous ranges per XCD
__device__ __forceinline__ int xcd_swizzle(int bid, int nwg) {
    const int q = nwg >> 3, r = nwg & 7;
    const int xcd = bid & 7, idx = bid >> 3;
    const int base = (xcd < r) ? xcd * (q + 1) : r * (q + 1) + (xcd - r) * q;
    return base + idx;
}

// ---- prep: transpose tail-MLP weights to bf16 [f][k] ----
__global__ void k_prepw(const float* __restrict__ in2f, const float* __restrict__ f2ow,
                        const float* __restrict__ dnsw,
                        uint16_t* __restrict__ in2ft, uint16_t* __restrict__ f2ot,
                        uint16_t* __restrict__ dnst) {
    int t = blockIdx.x * 256 + threadIdx.x;
    if (t < L_ * F_ * F_) {
        int k = t & (F_ - 1); int f = (t >> 7) & (F_ - 1); int l = t >> 14;
        const size_t src = (size_t)(l * F_ + k) * F_ + f;
        in2ft[t] = f2bf(in2f[src]);
        f2ot[t]  = f2bf(f2ow[src]);
        dnst[t]  = f2bf(dnsw[src]);
    }
}

// ---- build filter table: T[l][i][f] = (ssp(fij(r_i)@W1+b1)@W2+b2)[f], exact fp32 ----
// grid = L_*128 WGs, 256 thr; WG handles 16 consecutive r-rows of layer l.
__global__ __launch_bounds__(256) void k_build(
        const float* __restrict__ fw1, const float* __restrict__ fb1,
        const float* __restrict__ fw2, const float* __restrict__ fb2,
        float* __restrict__ T)
{
    const int l = blockIdx.x >> 7;
    const int rbase = (blockIdx.x & 127) * 16;
    const int c = threadIdx.x & 127;
    const int h = threadIdx.x >> 7;        // 0/1: two rows per iteration
    __shared__ float H_s[2][128];
    const float* w1 = fw1 + (size_t)l * G_ * F_;
    const float* w2 = fw2 + (size_t)l * F_ * F_;
    const float b1v = fb1[l * F_ + c];
    const float b2v = fb2[l * F_ + c];
    float w1c[G_];
#pragma unroll
    for (int k = 0; k < G_; ++k) w1c[k] = w1[k * F_ + c];
    const float step = 3.8f / 24.0f;
    const float coef = -0.5f / (step * step);
    for (int it = 0; it < 8; ++it) {
        const int row = rbase + it * 2 + h;
        const float r = (float)row * DELTA_;
        float a = b1v;
#pragma unroll
        for (int k = 0; k < G_; ++k) {
            const float d = r - (OFF0_ + step * (float)k);
            a = fmaf(__expf(coef * d * d), w1c[k], a);
        }
        H_s[h][c] = sspf(a);
        __syncthreads();
        float phi = b2v;
        for (int k = 0; k < F_; ++k)
            phi = fmaf(H_s[h][k], w2[k * F_ + c], phi);
        T[((size_t)l * NT_ + row) * F_ + c] = phi;
        __syncthreads();
    }
}

// ---- embed + first projection: x = emb[Z]; y0 = x @ in2f[0]^T (MFMA) ----
__global__ __launch_bounds__(256) void k_embed_proj(
        const float* __restrict__ emb, const int* __restrict__ Z,
        const uint16_t* __restrict__ in2ft0,
        float* __restrict__ x, float* __restrict__ y)
{
    const int wave = threadIdx.x >> 6;
    const int lane = threadIdx.x & 63;
    const int row  = lane & 15;
    const int kg   = lane >> 4;
    const int rb   = blockIdx.x * 64 + wave * 16;
    const int zr   = Z[rb + row];

    f32x4 acc[8];
#pragma unroll
    for (int nt = 0; nt < 8; ++nt) acc[nt] = (f32x4){0.f, 0.f, 0.f, 0.f};
#pragma unroll
    for (int ks = 0; ks < 4; ++ks) {
        const float* ep = emb + (size_t)zr * F_ + ks * 32 + kg * 8;
        float4 e0 = *(const float4*)ep;
        float4 e1 = *(const float4*)(ep + 4);
        bf16x8 a;
        a[0] = (__bf16)e0.x; a[1] = (__bf16)e0.y; a[2] = (__bf16)e0.z; a[3] = (__bf16)e0.w;
        a[4] = (__bf16)e1.x; a[5] = (__bf16)e1.y; a[6] = (__bf16)e1.z; a[7] = (__bf16)e1.w;
#pragma unroll
        for (int nt = 0; nt < 8; ++nt) {
            bf16x8 bfr = *(const bf16x8*)(in2ft0 + (nt * 16 + row) * F_ + ks * 32 + kg * 8);
            acc[nt] = __builtin_amdgcn_mfma_f32_16x16x32_bf16(a, bfr, acc[nt], 0, 0, 0);
        }
    }
#pragma unroll
    for (int nt = 0; nt < 8; ++nt)
#pragma unroll
        for (int j = 0; j < 4; ++j)
            y[(size_t)(rb + kg * 4 + j) * F_ + nt * 16 + row] = acc[nt][j];

    const int rb0 = blockIdx.x * 64;
#pragma unroll
    for (int i = 0; i < 32; ++i) {
        int idx = i * 256 + threadIdx.x;      // 0..8191
        int p = rb0 + (idx >> 7), f = idx & 127;
        x[(size_t)p * F_ + f] = emb[(size_t)Z[p] * F_ + f];
    }
}

// ---- fused layer: table-interp CFConv + atom MLP + next-layer projection ----
// WG = 512 thr = 8 waves = 8 atoms. Wave = atom: lane = edge for RBF/cutoff,
// then wave-uniform loop over LIVE edges only (ballot; ~30% survive cutoff):
// W[f] = lerp(T[i0], T[i0+1]) * fcut, acc[f] += W[f]*y[nbr][f] in registers.
// Tail: 3 MFMA GEMMs on 8 atom-rows (pad 16) as in round 16.
__global__ __launch_bounds__(512) void k_layer_full(
        const float* __restrict__ pos, const int* __restrict__ nbr,
        const float* __restrict__ mask, const float* __restrict__ y,
        const float* __restrict__ Tl,
        const uint16_t* __restrict__ f2ot, const float* __restrict__ ba,
        const uint16_t* __restrict__ dnst, const float* __restrict__ bb,
        const uint16_t* __restrict__ in2ftN,   // next-layer proj weights or null
        float* __restrict__ x, float* __restrict__ yout, float* __restrict__ out)
{
    __shared__ __align__(16) uint16_t abf[8 * 136];   // agg rows, bf16, stride 136
    __shared__ __align__(16) uint16_t mlpH[16 * 128]; // swizzled H tile
    __shared__ __align__(16) float    mlpX[8 * 136];  // x_new rows, stride 136

    const int wave = threadIdx.x >> 6;
    const int lane = threadIdx.x & 63;
    const int bid  = xcd_swizzle(blockIdx.x, NWG_);
    const int a0   = bid * 8;
    const int atom = a0 + wave;
    const int molbase = atom & ~(A_ - 1);

    // ---- phase A: per-lane edge data (lane = edge) ----
    const int e = atom * N_ + lane;
    const int jrow = molbase + nbr[e];
    const float dx = pos[jrow * 3 + 0] - pos[atom * 3 + 0];
    const float dy = pos[jrow * 3 + 1] - pos[atom * 3 + 1];
    const float dz = pos[jrow * 3 + 2] - pos[atom * 3 + 2];
    const float r = sqrtf(dx * dx + dy * dy + dz * dz + 1e-9f);
    const float fcm = (r <= CUTOFF_) ? mask[e] : 0.0f;
    float u = fminf(r * INVD_, 2046.999f);
    const int i0 = (int)u;
    const float wf = u - (float)i0;

    // ---- phase B: live-edge loop; lane owns feature pair (2*lane, 2*lane+1) ----
    unsigned long long live = __ballot(fcm != 0.0f);
    float ax = 0.0f, ay = 0.0f;
    while (live) {
        const int el = __builtin_ctzll(live); live &= (live - 1);
        const int   i0e = __shfl(i0, el);
        const float we  = __shfl(wf, el);
        const float fce = __shfl(fcm, el);
        const int   je  = __shfl(jrow, el);
        const float2 ta = *(const float2*)(Tl + (size_t)i0e * F_ + lane * 2);
        const float2 tb = *(const float2*)(Tl + (size_t)(i0e + 1) * F_ + lane * 2);
        const float2 yv = *(const float2*)(y + (size_t)je * F_ + lane * 2);
        const float w0 = fmaf(we, tb.x - ta.x, ta.x) * fce;
        const float w1 = fmaf(we, tb.y - ta.y, ta.y) * fce;
        ax = fmaf(w0, yv.x, ax);
        ay = fmaf(w1, yv.y, ay);
    }
    // agg row -> bf16 pair in LDS
    *(uint32_t*)((char*)abf + wave * 272 + lane * 4) =
        (uint32_t)f2bf(ax) | ((uint32_t)f2bf(ay) << 16);
    __syncthreads();   // barrier 1: abf complete

    // ---- tail MLP on 8 atom-rows (pad to 16; dup rows discarded) ----
    const int row  = lane & 15;
    const int kg   = lane >> 4;
    const int fcol = wave * 16 + row;      // this wave's output column
    const int r8   = row & 7;

    // GEMM_a: H = ssp(abf @ f2o + ba)
    {
        const float bav = ba[fcol];
        f32x4 acc = {bav, bav, bav, bav};
#pragma unroll
        for (int ks = 0; ks < 4; ++ks) {
            bf16x8 a = *(const bf16x8*)((const char*)abf + r8 * 272 + ks * 64 + kg * 16);
            bf16x8 bfr = *(const bf16x8*)(f2ot + fcol * F_ + ks * 32 + kg * 8);
            acc = __builtin_amdgcn_mfma_f32_16x16x32_bf16(a, bfr, acc, 0, 0, 0);
        }
#pragma unroll
        for (int j = 0; j < 4; ++j) {
            const int rr = kg * 4 + j;
            const int byt = rr * 256 + ((fcol * 2) ^ ((rr & 7) << 4));
            *(uint16_t*)((char*)mlpH + byt) = f2bf(sspf(acc[j]));
        }
    }
    __syncthreads();   // barrier 2: mlpH complete

    // GEMM_b: x_new = H @ dns + bb + x
    {
        const float bbv = bb[fcol];
        f32x4 acc = {bbv, bbv, bbv, bbv};
#pragma unroll
        for (int ks = 0; ks < 4; ++ks) {
            const int kbyte = ks * 64 + kg * 16;
            bf16x8 a2 = *(const bf16x8*)((char*)mlpH + row * 256 + (kbyte ^ ((row & 7) << 4)));
            bf16x8 bfr = *(const bf16x8*)(dnst + fcol * F_ + ks * 32 + kg * 8);
            acc = __builtin_amdgcn_mfma_f32_16x16x32_bf16(a2, bfr, acc, 0, 0, 0);
        }
        if (kg < 2) {
#pragma unroll
            for (int j = 0; j < 4; ++j) {
                const int ra = kg * 4 + j;     // 0..7
                const size_t idx = (size_t)(a0 + ra) * F_ + fcol;
                const float val = acc[j] + x[idx];
                x[idx] = val;
                mlpX[ra * 136 + fcol] = val;
                if (out) out[idx] = val;
            }
        }
    }

    // GEMM_c: y_next = x_new @ in2f[l+1]
    if (in2ftN) {
        __syncthreads();   // barrier 3: mlpX complete (uniform branch)
        f32x4 acc = {0.f, 0.f, 0.f, 0.f};
#pragma unroll
        for (int ks = 0; ks < 4; ++ks) {
            const float* xp = mlpX + r8 * 136 + ks * 32 + kg * 8;
            float4 u0 = *(const float4*)xp;
            float4 u1 = *(const float4*)(xp + 4);
            bf16x8 a;
            a[0] = (__bf16)u0.x; a[1] = (__bf16)u0.y; a[2] = (__bf16)u0.z; a[3] = (__bf16)u0.w;
            a[4] = (__bf16)u1.x; a[5] = (__bf16)u1.y; a[6] = (__bf16)u1.z; a[7] = (__bf16)u1.w;
            bf16x8 bfr = *(const bf16x8*)(in2ftN + fcol * F_ + ks * 32 + kg * 8);
            acc = __builtin_amdgcn_mfma_f32_16x16x32_bf16(a, bfr, acc, 0, 0, 0);
        }
        if (kg < 2) {
#pragma unroll
            for (int j = 0; j < 4; ++j)
                yout[(size_t)(a0 + kg * 4 + j) * F_ + fcol] = acc[j];
        }
    }
}

extern "C" void kernel_launch(void* const* d_in, const int* in_sizes, int n_in,
                              void* d_out, int out_size, void* d_ws, size_t ws_size,
                              hipStream_t stream) {
    const float* emb   = (const float*)d_in[0];
    const float* pos   = (const float*)d_in[1];
    const float* fw1   = (const float*)d_in[2];
    const float* fb1   = (const float*)d_in[3];
    const float* fw2   = (const float*)d_in[4];
    const float* fb2   = (const float*)d_in[5];
    const float* in2f  = (const float*)d_in[6];
    const float* f2o_w = (const float*)d_in[7];
    const float* f2o_b = (const float*)d_in[8];
    const float* dns_w = (const float*)d_in[9];
    const float* dns_b = (const float*)d_in[10];
    const int*   Z     = (const int*)d_in[11];
    const int*   nbrs  = (const int*)d_in[12];
    const float* mask  = (const float*)d_in[13];

    char* ws = (char*)d_ws;
    size_t off = 0;
    auto alloc = [&](size_t bytes) {
        char* p = ws + off; off += (bytes + 255) & ~(size_t)255; return p;
    };
    float*    x     = (float*)   alloc((size_t)P_ * F_ * 4);
    float*    y0    = (float*)   alloc((size_t)P_ * F_ * 4);
    float*    y1    = (float*)   alloc((size_t)P_ * F_ * 4);
    float*    T     = (float*)   alloc((size_t)L_ * NT_ * F_ * 4);   // 3 MB
    uint16_t* in2ft = (uint16_t*)alloc((size_t)L_ * F_ * F_ * 2);
    uint16_t* f2ot  = (uint16_t*)alloc((size_t)L_ * F_ * F_ * 2);
    uint16_t* dnst  = (uint16_t*)alloc((size_t)L_ * F_ * F_ * 2);
    // total scratch: ~9.5 MB

    k_prepw<<<192, 256, 0, stream>>>(in2f, f2o_w, dns_w, in2ft, f2ot, dnst);
    k_build<<<L_ * 128, 256, 0, stream>>>(fw1, fb1, fw2, fb2, T);
    k_embed_proj<<<P_ / 64, 256, 0, stream>>>(emb, Z, in2ft, x, y0);

    float* ycur = y0;
    float* ynxt = y1;
    for (int l = 0; l < L_; ++l) {
        k_layer_full<<<NWG_, 512, 0, stream>>>(
            pos, nbrs, mask, ycur,
            T + (size_t)l * NT_ * F_,
            f2ot + (size_t)l * F_ * F_, f2o_b + (size_t)l * F_,
            dnst + (size_t)l * F_ * F_, dns_b + (size_t)l * F_,
            (l < L_ - 1) ? (in2ft + (size_t)(l + 1) * F_ * F_) : nullptr,
            x, ynxt, (l == L_ - 1) ? (float*)d_out : nullptr);
        float* t = ycur; ycur = ynxt; ynxt = t;
    }
}